// Round 3
// baseline (275.589 us; speedup 1.0000x reference)
//
#include <hip/hip_runtime.h>
#include <cstdint>
#include <cstddef>

#define Bn 16
#define Cn 64
#define Hn 256
#define Wn 256
#define HWn (Hn * Wn)          // 65536
#define PIX (Bn * HWn)         // 1048576

#define TH 8
#define TW 64
#define NB_CHUNK 4             // batches per chunk (L3 blocking)

// ---------------- kernel C: pack weight signs + scaling + border corrections ----
__global__ __launch_bounds__(64) void pack_weights(const float* __restrict__ w,
                                                   const float* __restrict__ b0g,
                                                   const float* __restrict__ pwg,
                                                   const float* __restrict__ b1g,
                                                   uint64_t* __restrict__ wbits,
                                                   float4* __restrict__ par,
                                                   int* __restrict__ corr) {
    const int co = blockIdx.x;
    const int ci = threadIdx.x;
    const float* wp = w + ((size_t)co * Cn + ci) * 9;
    float v[9];
    float asum = 0.f;
    #pragma unroll
    for (int t = 0; t < 9; ++t) { v[t] = wp[t]; asum += fabsf(v[t]); }
    uint64_t m[9];
    #pragma unroll
    for (int t = 0; t < 9; ++t) m[t] = __ballot(v[t] > 0.f);
    #pragma unroll
    for (int off = 32; off; off >>= 1) asum += __shfl_xor(asum, off);
    if (ci == 0) {
        #pragma unroll
        for (int t = 0; t < 9; ++t) {
            wbits[co * 9 + t] = m[t];
            corr[co * 9 + t]  = 64 - 2 * (int)__popcll(m[t]);
        }
        par[co] = make_float4(asum * (1.f / (Cn * 9)), b0g[co], pwg[co], b1g[co]);
    }
}

// ---------------- kernel A: binarize + bit-pack activations (one chunk) --------
__global__ __launch_bounds__(256) void pack_act(const float* __restrict__ x,
                                                const float* __restrict__ rdk,
                                                const float* __restrict__ rdb,
                                                uint64_t* __restrict__ actbits,
                                                int n_base) {
    int t = blockIdx.x * 256 + threadIdx.x;     // 0 .. NB_CHUNK*HWn/4-1
    int p0 = t << 2;                            // chunk-local pixel, multiple of 4
    int n  = n_base + (p0 >> 16);
    int hw = p0 & (HWn - 1);
    const float* xb = x + (size_t)n * Cn * HWn + hw;
    uint64_t b0 = 0, b1 = 0, b2 = 0, b3 = 0;
    for (int ci = 0; ci < Cn; ++ci) {
        float k  = rdk[ci];
        float bb = rdb[ci];
        const float4 v = *reinterpret_cast<const float4*>(xb + (size_t)ci * HWn);
        uint64_t bit = 1ull << ci;
        if (fmaf(v.x, k, bb) > 0.f) b0 |= bit;
        if (fmaf(v.y, k, bb) > 0.f) b1 |= bit;
        if (fmaf(v.z, k, bb) > 0.f) b2 |= bit;
        if (fmaf(v.w, k, bb) > 0.f) b3 |= bit;
    }
    uint64_t* o = actbits + (size_t)n * HWn + hw;
    o[0] = b0; o[1] = b1; o[2] = b2; o[3] = b3;
}

// ---------------- kernel B: XNOR-popcount conv + fused epilogue (one chunk) ----
__global__ __launch_bounds__(256) void bconv(const uint64_t* __restrict__ actbits,
                                             const uint64_t* __restrict__ wbits,
                                             const float4* __restrict__ par,
                                             const int* __restrict__ corr,
                                             const float* __restrict__ x,
                                             float* __restrict__ out,
                                             int n_base) {
    __shared__ uint64_t s_a[TH + 2][TW + 2];   // zero-filled halo for OOB
    __shared__ float4 s_par[Cn];

    const int tid = threadIdx.x;
    const int w0 = blockIdx.x * TW;
    const int h0 = blockIdx.y * TH;
    const int n  = n_base + blockIdx.z;

    for (int i = tid; i < (TH + 2) * (TW + 2); i += 256) {
        int r = i / (TW + 2), c = i % (TW + 2);
        int gh = h0 - 1 + r, gw = w0 - 1 + c;
        uint64_t a = 0;
        if (gh >= 0 && gh < Hn && gw >= 0 && gw < Wn)
            a = actbits[(size_t)n * HWn + gh * Wn + gw];
        s_a[r][c] = a;
    }
    if (tid < Cn) s_par[tid] = par[tid];
    __syncthreads();

    const int lane = tid & 63;
    const int co_base = __builtin_amdgcn_readfirstlane((tid >> 6) * 16);
    const int w = w0 + lane;
    const unsigned cmask = (w == 0) ? 0x49u : (w == Wn - 1 ? 0x124u : 0u);
    const int edge_h = (h0 == 0) | (h0 + TH == Hn);
    const int any_edge = (cmask != 0) | edge_h;  // block-uniform-ish fast test

    for (int c2 = 0; c2 < 8; ++c2) {
        const int coA = co_base + c2 * 2;
        // weight bits: uniform address -> scalar loads, stay in SGPRs across rows
        const uint64_t* wbp = wbits + (size_t)coA * 9;
        uint64_t wba[9], wbb[9];
        #pragma unroll
        for (int t = 0; t < 9; ++t) { wba[t] = wbp[t]; wbb[t] = wbp[9 + t]; }
        const float4 pA = s_par[coA];
        const float4 pB = s_par[coA + 1];

        // hoist 16 residual x loads (2 co x 8 rows) -> overlap with popcounts
        const float* xpc = x + ((size_t)(n * Cn + coA)) * HWn + (size_t)h0 * Wn + w;
        float* opc = out + ((size_t)(n * Cn + coA)) * HWn + (size_t)h0 * Wn + w;
        float xv[16];
        #pragma unroll
        for (int j = 0; j < 2; ++j)
            #pragma unroll
            for (int rr = 0; rr < TH; ++rr)
                xv[j * 8 + rr] = xpc[(size_t)j * HWn + (size_t)rr * Wn];

        uint64_t A0[3], A1[3];
        #pragma unroll
        for (int dw = 0; dw < 3; ++dw) {
            A0[dw] = s_a[0][lane + dw];
            A1[dw] = s_a[1][lane + dw];
        }
        #pragma unroll
        for (int r = 0; r < TH; ++r) {
            uint64_t A2[3];
            #pragma unroll
            for (int dw = 0; dw < 3; ++dw) A2[dw] = s_a[r + 2][lane + dw];

            int accA = 0, accB = 0;
            #pragma unroll
            for (int dw = 0; dw < 3; ++dw) {
                accA += (int)__popcll(A0[dw] ^ wba[dw]);
                accA += (int)__popcll(A1[dw] ^ wba[3 + dw]);
                accA += (int)__popcll(A2[dw] ^ wba[6 + dw]);
                accB += (int)__popcll(A0[dw] ^ wbb[dw]);
                accB += (int)__popcll(A1[dw] ^ wbb[3 + dw]);
                accB += (int)__popcll(A2[dw] ^ wbb[6 + dw]);
            }
            int isumA = 576 - 2 * accA;
            int isumB = 576 - 2 * accB;

            if (any_edge) {
                const int h = h0 + r;
                const unsigned imask = cmask |
                    ((h == 0) ? 0x7u : (h == Hn - 1 ? 0x1C0u : 0u));
                if (__any((int)imask)) {
                    #pragma unroll
                    for (int t = 0; t < 9; ++t)
                        if (imask & (1u << t)) {
                            isumA -= corr[coA * 9 + t];
                            isumB -= corr[(coA + 1) * 9 + t];
                        }
                }
            }

            float yA = fmaf(pA.x, (float)isumA, pA.y);
            yA = (yA >= 0.f) ? yA : yA * pA.z;
            yA += pA.w;
            float yB = fmaf(pB.x, (float)isumB, pB.y);
            yB = (yB >= 0.f) ? yB : yB * pB.z;
            yB += pB.w;
            opc[(size_t)r * Wn]       = yA + xv[r];
            opc[HWn + (size_t)r * Wn] = yB + xv[8 + r];

            #pragma unroll
            for (int dw = 0; dw < 3; ++dw) { A0[dw] = A1[dw]; A1[dw] = A2[dw]; }
        }
    }
}

// ---------------- host launcher ----------------
extern "C" void kernel_launch(void* const* d_in, const int* in_sizes, int n_in,
                              void* d_out, int out_size, void* d_ws, size_t ws_size,
                              hipStream_t stream) {
    const float* x      = (const float*)d_in[0];
    const float* rd_k   = (const float*)d_in[1];
    const float* rd_b   = (const float*)d_in[2];
    // d_in[3] = beta: unused in forward (STE forward = hard sign)
    const float* conv_w = (const float*)d_in[4];
    const float* pb0    = (const float*)d_in[5];
    const float* pw     = (const float*)d_in[6];
    const float* pb1    = (const float*)d_in[7];
    float* out = (float*)d_out;

    uint8_t* ws = (uint8_t*)d_ws;
    uint64_t* actbits = (uint64_t*)ws;                                   // 8 MiB
    size_t off = (size_t)PIX * 8;
    uint64_t* wbits = (uint64_t*)(ws + off); off += (size_t)Cn * 9 * 8;  // 4608 B
    float4*   par   = (float4*)(ws + off);   off += (size_t)Cn * 16;     // 1024 B
    int*      corr  = (int*)(ws + off);                                  // 2304 B

    pack_weights<<<Cn, 64, 0, stream>>>(conv_w, pb0, pw, pb1, wbits, par, corr);

    const int packBlocks = NB_CHUNK * HWn / 4 / 256;   // 256
    dim3 gB(Wn / TW, Hn / TH, NB_CHUNK);
    for (int ch = 0; ch < Bn / NB_CHUNK; ++ch) {
        pack_act<<<packBlocks, 256, 0, stream>>>(x, rd_k, rd_b, actbits,
                                                 ch * NB_CHUNK);
        bconv<<<gB, 256, 0, stream>>>(actbits, wbits, par, corr, x, out,
                                      ch * NB_CHUNK);
    }
}

// Round 4
// 194.334 us; speedup vs baseline: 1.4181x; 1.4181x over previous
//
#include <hip/hip_runtime.h>
#include <cstdint>
#include <cstddef>

#define Bn 16
#define Cn 64
#define Hn 256
#define Wn 256
#define HWn (Hn * Wn)          // 65536
#define PIX (Bn * HWn)         // 1048576

#define TH 8
#define TW 64

// ---------------- kernel C: pack weight signs + scaling + border corrections ----
__global__ __launch_bounds__(64) void pack_weights(const float* __restrict__ w,
                                                   const float* __restrict__ b0g,
                                                   const float* __restrict__ pwg,
                                                   const float* __restrict__ b1g,
                                                   uint64_t* __restrict__ wbits,
                                                   float4* __restrict__ par,
                                                   int* __restrict__ corr) {
    const int co = blockIdx.x;
    const int ci = threadIdx.x;
    const float* wp = w + ((size_t)co * Cn + ci) * 9;
    float v[9];
    float asum = 0.f;
    #pragma unroll
    for (int t = 0; t < 9; ++t) { v[t] = wp[t]; asum += fabsf(v[t]); }
    uint64_t m[9];
    #pragma unroll
    for (int t = 0; t < 9; ++t) m[t] = __ballot(v[t] > 0.f);
    #pragma unroll
    for (int off = 32; off; off >>= 1) asum += __shfl_xor(asum, off);
    if (ci == 0) {
        #pragma unroll
        for (int t = 0; t < 9; ++t) {
            wbits[co * 9 + t] = m[t];
            corr[co * 9 + t]  = 64 - 2 * (int)__popcll(m[t]);
        }
        par[co] = make_float4(asum * (1.f / (Cn * 9)), b0g[co], pwg[co], b1g[co]);
    }
}

// ---------------- fused kernel: in-block pack + XNOR conv + epilogue ----------
__global__ __launch_bounds__(256) void fused(const float* __restrict__ x,
                                             const float* __restrict__ rdk,
                                             const float* __restrict__ rdb,
                                             const uint64_t* __restrict__ wbits,
                                             const float4* __restrict__ par,
                                             const int* __restrict__ corr,
                                             float* __restrict__ out) {
    __shared__ uint64_t s_a[TH + 2][TW + 2];   // activation bits, zero halo at borders
    __shared__ float4 s_par[Cn];
    __shared__ float2 s_rd[Cn];

    const int tid = threadIdx.x;
    const int w0 = blockIdx.x * TW;
    const int h0 = blockIdx.y * TH;
    const int n  = blockIdx.z;

    if (tid < Cn) {
        s_par[tid] = par[tid];
        s_rd[tid]  = make_float2(rdk[tid], rdb[tid]);
    }
    __syncthreads();

    // -------- phase 1: binarize+pack the 10x66 halo tile directly from x ------
    // tasks 0..319: interior pixel-pairs (10 rows x 32 pairs), float2 coalesced
    // tasks 320..339: halo columns (10 rows x 2), scalar
    const float* xn = x + (size_t)n * Cn * HWn;
    for (int task = tid; task < 340; task += 256) {
        if (task < 320) {
            const int r  = task >> 5;            // 0..9
            const int pp = task & 31;            // pair within row
            const int gh = h0 - 1 + r;
            const int gw = w0 + pp * 2;          // even -> 8B aligned
            uint64_t b0 = 0, b1 = 0;
            if (gh >= 0 && gh < Hn) {
                const float* xp = xn + (size_t)gh * Wn + gw;
                #pragma unroll 8
                for (int ci = 0; ci < Cn; ++ci) {
                    const float2 v = *reinterpret_cast<const float2*>(xp + (size_t)ci * HWn);
                    const float2 kb = s_rd[ci];
                    const uint64_t bit = 1ull << ci;
                    if (fmaf(v.x, kb.x, kb.y) > 0.f) b0 |= bit;
                    if (fmaf(v.y, kb.x, kb.y) > 0.f) b1 |= bit;
                }
            }
            s_a[r][1 + 2 * pp] = b0;
            s_a[r][2 + 2 * pp] = b1;
        } else {
            const int t2 = task - 320;
            const int r = t2 >> 1;
            const int side = t2 & 1;             // 0: col 0 (gw=w0-1), 1: col 65
            const int gh = h0 - 1 + r;
            const int gw = side ? (w0 + TW) : (w0 - 1);
            uint64_t b = 0;
            if (gh >= 0 && gh < Hn && gw >= 0 && gw < Wn) {
                const float* xp = xn + (size_t)gh * Wn + gw;
                #pragma unroll 8
                for (int ci = 0; ci < Cn; ++ci) {
                    const float v = xp[(size_t)ci * HWn];
                    const float2 kb = s_rd[ci];
                    if (fmaf(v, kb.x, kb.y) > 0.f) b |= 1ull << ci;
                }
            }
            s_a[r][side ? (TW + 1) : 0] = b;
        }
    }
    __syncthreads();

    // -------- phase 2: XNOR-popcount conv, A-window in registers --------------
    const int lane = tid & 63;
    const int co_base = __builtin_amdgcn_readfirstlane((tid >> 6) * 16);
    const int w = w0 + lane;
    const unsigned cmask = (w == 0) ? 0x49u : (w == Wn - 1 ? 0x124u : 0u);
    const int any_edge = (w0 == 0) | (w0 + TW == Wn) | (h0 == 0) | (h0 + TH == Hn);

    uint64_t A[TH + 2][3];
    #pragma unroll
    for (int r = 0; r < TH + 2; ++r)
        #pragma unroll
        for (int dw = 0; dw < 3; ++dw)
            A[r][dw] = s_a[r][lane + dw];

    const size_t base_n = (size_t)n * Cn * HWn + (size_t)h0 * Wn + w;

    for (int c2 = 0; c2 < 8; ++c2) {
        const int coA = co_base + c2 * 2;
        // uniform address -> scalar loads, resident in SGPRs for the whole pair
        const uint64_t* wbp = wbits + (size_t)coA * 9;
        uint64_t wba[9], wbb[9];
        #pragma unroll
        for (int t = 0; t < 9; ++t) { wba[t] = wbp[t]; wbb[t] = wbp[9 + t]; }
        const float4 pA = s_par[coA];
        const float4 pB = s_par[coA + 1];

        // hoist residual x loads (2 co x 8 rows) so they fly during popcounts
        const float* xpc = x + base_n + (size_t)coA * HWn;
        float* opc = out + base_n + (size_t)coA * HWn;
        float xv[16];
        #pragma unroll
        for (int j = 0; j < 2; ++j)
            #pragma unroll
            for (int rr = 0; rr < TH; ++rr)
                xv[j * 8 + rr] = xpc[(size_t)j * HWn + (size_t)rr * Wn];

        #pragma unroll
        for (int r = 0; r < TH; ++r) {
            int accA = 0, accB = 0;
            #pragma unroll
            for (int dh = 0; dh < 3; ++dh)
                #pragma unroll
                for (int dw = 0; dw < 3; ++dw) {
                    accA += (int)__popcll(A[r + dh][dw] ^ wba[dh * 3 + dw]);
                    accB += (int)__popcll(A[r + dh][dw] ^ wbb[dh * 3 + dw]);
                }
            int isumA = 576 - 2 * accA;
            int isumB = 576 - 2 * accB;

            if (any_edge) {
                const int h = h0 + r;
                const unsigned imask = cmask |
                    ((h == 0) ? 0x7u : (h == Hn - 1 ? 0x1C0u : 0u));
                if (__any((int)imask)) {
                    #pragma unroll
                    for (int t = 0; t < 9; ++t)
                        if (imask & (1u << t)) {
                            isumA -= corr[coA * 9 + t];
                            isumB -= corr[(coA + 1) * 9 + t];
                        }
                }
            }

            float yA = fmaf(pA.x, (float)isumA, pA.y);
            yA = (yA >= 0.f) ? yA : yA * pA.z;
            yA += pA.w;
            float yB = fmaf(pB.x, (float)isumB, pB.y);
            yB = (yB >= 0.f) ? yB : yB * pB.z;
            yB += pB.w;
            opc[(size_t)r * Wn]       = yA + xv[r];
            opc[HWn + (size_t)r * Wn] = yB + xv[8 + r];
        }
    }
}

// ---------------- host launcher ----------------
extern "C" void kernel_launch(void* const* d_in, const int* in_sizes, int n_in,
                              void* d_out, int out_size, void* d_ws, size_t ws_size,
                              hipStream_t stream) {
    const float* x      = (const float*)d_in[0];
    const float* rd_k   = (const float*)d_in[1];
    const float* rd_b   = (const float*)d_in[2];
    // d_in[3] = beta: unused in forward (STE forward = hard sign)
    const float* conv_w = (const float*)d_in[4];
    const float* pb0    = (const float*)d_in[5];
    const float* pw     = (const float*)d_in[6];
    const float* pb1    = (const float*)d_in[7];
    float* out = (float*)d_out;

    uint8_t* ws = (uint8_t*)d_ws;
    uint64_t* wbits = (uint64_t*)ws;                       // 4608 B
    float4*   par   = (float4*)(ws + 4608);                // 1024 B
    int*      corr  = (int*)(ws + 4608 + 1024);            // 2304 B

    pack_weights<<<Cn, 64, 0, stream>>>(conv_w, pb0, pw, pb1, wbits, par, corr);
    dim3 gB(Wn / TW, Hn / TH, Bn);
    fused<<<gB, 256, 0, stream>>>(x, rd_k, rd_b, wbits, par, corr, out);
}